// Round 17
// baseline (119.757 us; speedup 1.0000x reference)
//
#include <hip/hip_runtime.h>

typedef unsigned short u16;
typedef __attribute__((ext_vector_type(8))) __bf16 bf16x8;
typedef __attribute__((ext_vector_type(8))) short s16x8;
typedef __attribute__((ext_vector_type(8))) unsigned short u16x8;
typedef __attribute__((ext_vector_type(4))) float f32x4;
typedef __attribute__((ext_vector_type(4))) unsigned short u16x4;
typedef __attribute__((ext_vector_type(4))) float fl4;
typedef __attribute__((ext_vector_type(4))) int i32x4;
typedef __attribute__((ext_vector_type(4))) unsigned char u8x4;

#define MFMA(a, b, c) __builtin_amdgcn_mfma_f32_16x16x32_bf16((a), (b), (c), 0, 0, 0)
// 0.125 * log2(e): folds 1/sqrt(dk) and the exp->exp2 conversion into Q
#define QSC 0.18033688011112042f

// native RNE float->bf16
__device__ __forceinline__ u16 f2bf(float f) {
  __bf16 h = (__bf16)f;
  return __builtin_bit_cast(unsigned short, h);
}

__device__ __forceinline__ float bf2f(u16 u) {
  union { unsigned u; float f; } v; v.u = ((unsigned)u) << 16;
  return v.f;
}

__device__ __forceinline__ void gll16(const u16* g, u16* l) {
  typedef __attribute__((address_space(1))) unsigned int gu32;
  typedef __attribute__((address_space(3))) unsigned int lu32;
  __builtin_amdgcn_global_load_lds((gu32*)g, (lu32*)l, 16, 0, 0);
}

// ---------------- weight convert ----------------

__global__ __launch_bounds__(256) void k_convert_w(
    const float* __restrict__ Wq, const float* __restrict__ Wk,
    const float* __restrict__ Wv, const float* __restrict__ Wo,
    u16* __restrict__ wqkv, u16* __restrict__ wob) {
  const int n = 3072 * 192;  // 3072 rows x 192 groups of 4
  for (int i = blockIdx.x * 256 + threadIdx.x; i < n; i += gridDim.x * 256) {
    int row = i / 192;
    int col = (i - row * 192) * 4;
    const float* src; u16* dst; float sc = 1.0f;
    if (row < 768)       { src = Wq + row * 768;          dst = wqkv + row * 768; sc = QSC; }
    else if (row < 1536) { src = Wk + (row - 768) * 768;  dst = wqkv + row * 768; }
    else if (row < 2304) { src = Wv + (row - 1536) * 768; dst = wqkv + row * 768; }
    else                 { src = Wo + (row - 2304) * 768; dst = wob + (row - 2304) * 768; }
    fl4 f = *(const fl4*)(src + col);
    u16x4 o;
    o[0] = f2bf(f[0] * sc); o[1] = f2bf(f[1] * sc);
    o[2] = f2bf(f[2] * sc); o[3] = f2bf(f[3] * sc);
    *(u16x4*)(dst + col) = o;
  }
}

// ---------------- fused QKV GEMM: f32-A via DMA, single barrier/iter --------
// 64x128 tile, BK=32, grid(1152) flat with XCD remap (1152 = 8*144).
// A staged as RAW f32 via global_load_lds into [64][32]-f32 LDS (8-chunk XOR
// swizzle: pos p of row r holds global chunk p^(r&7)); converted to bf16 at
// fragment-load time (2x ds_read_b128 + 8 scalar casts). No convert_x kernel,
// no reg-staging, no second barrier: the round-13-validated 1-barrier skeleton.

__global__ __launch_bounds__(256) void k_gemm_qkv(
    const float* __restrict__ xq, const float* __restrict__ xk,
    const float* __restrict__ xv, const u16* __restrict__ wqkv,
    const float* __restrict__ bq, const float* __restrict__ bk_,
    const float* __restrict__ bv_,
    u16* __restrict__ Qb, u16* __restrict__ Kb, u16* __restrict__ Vtb) {
  __shared__ __align__(16) float Af[2][64 * 32];   // 8 KB each
  __shared__ __align__(16) u16 Bbuf[2][128 * 32];  // 8 KB each
  const int tid = threadIdx.x;
  const int bid = blockIdx.x;
  const int wid = (bid & 7) * 144 + (bid >> 3);  // bijective: 1152 = 8*144
  const int row0 = (wid / 18) * 64, col0 = (wid % 18) * 128;
  const int seg = col0 / 768;
  const float* A32 = (seg == 0) ? xq : ((seg == 1) ? xk : xv);
  const int w = tid >> 6, lane = tid & 63, lr = lane & 15, kg = lane >> 4;
  const int wr = (w >> 1) * 32, wc = (w & 1) * 64;

  const int c0 = tid, c1 = tid + 256;
  // A chunks (16B = 4 f32): 512 chunks; chunk c -> row c>>3, pos c&7 holds global (c&7)^(row&7)
  const int arow0 = c0 >> 3, ag0 = (c0 & 7) ^ (arow0 & 7);
  const int arow1 = c1 >> 3, ag1 = (c1 & 7) ^ (arow1 & 7);
  const float* aS0 = A32 + (size_t)(row0 + arow0) * 768 + ag0 * 4;
  const float* aS1 = A32 + (size_t)(row0 + arow1) * 768 + ag1 * 4;
  // B chunks (16B = 8 bf16): round-12 algebra: row c>>2, pos c&3 <-> global (c&3)^((r>>1)&3)
  const int br0 = c0 >> 2, bg0 = (c0 & 3) ^ ((br0 >> 1) & 3);
  const int br1 = c1 >> 2, bg1 = (c1 & 3) ^ ((br1 >> 1) & 3);
  const u16* bS0 = wqkv + (size_t)(col0 + br0) * 768 + bg0 * 8;
  const u16* bS1 = wqkv + (size_t)(col0 + br1) * 768 + bg1 * 8;

  f32x4 acc[2][4];
  f32x4 zero = {0.f, 0.f, 0.f, 0.f};
#pragma unroll
  for (int i = 0; i < 2; i++)
#pragma unroll
    for (int j = 0; j < 4; j++) acc[i][j] = zero;

  // A fragment float-offsets: row r, lo chunk (2kg)^(r&7), hi chunk (2kg+1)^(r&7)
  int aoffL[2], aoffH[2], boff[4];
#pragma unroll
  for (int mi = 0; mi < 2; mi++) {
    int r = wr + mi * 16 + lr;
    aoffL[mi] = r * 32 + ((2 * kg) ^ (r & 7)) * 4;
    aoffH[mi] = r * 32 + ((2 * kg + 1) ^ (r & 7)) * 4;
  }
#pragma unroll
  for (int ni = 0; ni < 4; ni++) {
    int r = wc + ni * 16 + lr;
    boff[ni] = r * 32 + (kg ^ ((r >> 1) & 3)) * 8;
  }

#define STAGE(kt) { u16* ad = (u16*)Af[(kt)&1]; u16* bd = Bbuf[(kt)&1];   \
    gll16((const u16*)(aS0 + (kt) * 32), ad + c0 * 8);                    \
    gll16((const u16*)(aS1 + (kt) * 32), ad + c1 * 8);                    \
    gll16(bS0 + (kt) * 32, bd + c0 * 8);                                  \
    gll16(bS1 + (kt) * 32, bd + c1 * 8); }

  STAGE(0);
  __syncthreads();  // drains STAGE(0) DMA

  for (int kt = 0; kt < 24; kt++) {
    const int cur = kt & 1;
    if (kt < 23) STAGE(kt + 1);  // prefetch; latency hidden under compute
    bf16x8 af[2], bfr[4];
#pragma unroll
    for (int mi = 0; mi < 2; mi++) {
      fl4 lo = *(const fl4*)(Af[cur] + aoffL[mi]);
      fl4 hi = *(const fl4*)(Af[cur] + aoffH[mi]);
      u16x8 t;
      t[0] = f2bf(lo[0]); t[1] = f2bf(lo[1]); t[2] = f2bf(lo[2]); t[3] = f2bf(lo[3]);
      t[4] = f2bf(hi[0]); t[5] = f2bf(hi[1]); t[6] = f2bf(hi[2]); t[7] = f2bf(hi[3]);
      af[mi] = __builtin_bit_cast(bf16x8, t);
    }
#pragma unroll
    for (int ni = 0; ni < 4; ni++) bfr[ni] = *(const bf16x8*)(Bbuf[cur] + boff[ni]);
#pragma unroll
    for (int mi = 0; mi < 2; mi++)
#pragma unroll
      for (int ni = 0; ni < 4; ni++)
        acc[mi][ni] = MFMA(af[mi], bfr[ni], acc[mi][ni]);
    if (kt < 23) __syncthreads();  // next tile landed, reads of cur retired
  }
#undef STAGE

  const float* bias = (seg == 0) ? bq : ((seg == 1) ? bk_ : bv_);
  const float bsc = (seg == 0) ? QSC : 1.0f;
  const int ncol0 = col0 - seg * 768;
#pragma unroll
  for (int ni = 0; ni < 4; ni++) {
    const int n = ncol0 + wc + ni * 16 + lr;
    const float bval = bias[n] * bsc;
    const int hh = n >> 6, dk = n & 63;
#pragma unroll
    for (int mi = 0; mi < 2; mi++)
#pragma unroll
      for (int j = 0; j < 4; j++) {
        const int m = row0 + wr + mi * 16 + kg * 4 + j;
        const int bb = m >> 11, ss = m & 2047;
        const u16 val = f2bf(acc[mi][ni][j] + bval);
        if (seg == 0)
          Qb[((size_t)((bb * 12 + hh) * 2048 + ss)) * 64 + dk] = val;
        else if (seg == 1)
          Kb[((size_t)((bb * 12 + hh) * 2048 + ss)) * 64 + dk] = val;
        else
          Vtb[((size_t)((bb * 12 + hh) * 64 + dk)) * 2048 + ss] = val;
      }
  }
}

// ---------------- flash attention (round-15 passing version, unchanged) -----

__global__ __launch_bounds__(256) void k_attn(
    const u16* __restrict__ Qb, const u16* __restrict__ Kb,
    const u16* __restrict__ Vtb, const int* __restrict__ mask,
    u16* __restrict__ o_part, float* __restrict__ l_part) {
  __shared__ __align__(16) u16 Ks[2][64 * 64];
  __shared__ __align__(16) u16 Vs[2][64 * 64];
  __shared__ __align__(16) u16 Ps[4][32 * 64];
  __shared__ __align__(4) unsigned char mlds8[1024];
  const int bid = blockIdx.x;
  const int wid = (bid & 7) * 96 + (bid >> 3);  // bijective: 768 = 8*96
  const int qt = wid & 15;       // q-tile [0,16)
  const int gh = wid >> 4;       // (bh,half) group [0,48)
  const int bh = gh >> 1, half = gh & 1;
  const int b = bh / 12;
  const int kvb = half << 10;  // 0 or 1024
  const int tid = threadIdx.x, w = tid >> 6, lane = tid & 63;
  const int lr = lane & 15, g = lane >> 4;
  const int q0 = qt * 128 + w * 32;
  const u16* Qh = Qb + (size_t)bh * (2048 * 64);
  const u16* Kh = Kb + (size_t)bh * (2048 * 64);
  const u16* Vh = Vtb + (size_t)bh * (64 * 2048);
  const int* mb = mask + b * 2048;
  u16* Pw = Ps[w];

  // this block's mask half -> LDS as u8 (one i32x4 load -> u8x4 store)
  {
    i32x4 m4 = *(const i32x4*)(mb + kvb + tid * 4);
    u8x4 m8;
    m8[0] = (unsigned char)m4[0]; m8[1] = (unsigned char)m4[1];
    m8[2] = (unsigned char)m4[2]; m8[3] = (unsigned char)m4[3];
    *(u8x4*)(mlds8 + tid * 4) = m8;
  }

  bf16x8 aq[2][2];
#pragma unroll
  for (int mi = 0; mi < 2; mi++)
#pragma unroll
    for (int ks = 0; ks < 2; ks++)
      aq[mi][ks] = *(const bf16x8*)(Qh + (q0 + mi * 16 + lr) * 64 + ks * 32 + g * 8);

  f32x4 zero = {0.f, 0.f, 0.f, 0.f};
  f32x4 o[2][4];
#pragma unroll
  for (int mi = 0; mi < 2; mi++)
#pragma unroll
    for (int di = 0; di < 4; di++) o[mi][di] = zero;
  f32x4 o_l[2];
  o_l[0] = zero; o_l[1] = zero;

  // ones B-fragment for row-sum MFMA (bf16 1.0 = 0x3F80)
  s16x8 ov = {0x3F80, 0x3F80, 0x3F80, 0x3F80, 0x3F80, 0x3F80, 0x3F80, 0x3F80};
  bf16x8 ones = __builtin_bit_cast(bf16x8, ov);

  // staging coords: 512 chunks/tile; row c>>3, pos c&7 <-> global chunk (c&7)^(row&7)
  const int c0 = tid, c1 = tid + 256;
  const int sr0 = c0 >> 3, sg0 = (c0 & 7) ^ (sr0 & 7);
  const int sr1 = c1 >> 3, sg1 = (c1 & 7) ^ (sr1 & 7);
  const u16* kA0 = Kh + (size_t)kvb * 64 + sr0 * 64 + sg0 * 8;
  const u16* kA1 = Kh + (size_t)kvb * 64 + sr1 * 64 + sg1 * 8;
  const u16* vA0 = Vh + sr0 * 2048 + kvb + sg0 * 8;
  const u16* vA1 = Vh + sr1 * 2048 + kvb + sg1 * 8;

#define STAGE(u) { u16* kd = Ks[(u)&1]; u16* vd = Vs[(u)&1];           \
    gll16(kA0 + (u) * 4096, kd + c0 * 8);                              \
    gll16(kA1 + (u) * 4096, kd + c1 * 8);                              \
    gll16(vA0 + (u) * 64,  vd + c0 * 8);                               \
    gll16(vA1 + (u) * 64,  vd + c1 * 8); }

  STAGE(0);
  __syncthreads();  // drains STAGE(0) DMA + mlds8 writes; all waves synced

  for (int t = 0; t < 16; t++) {
    if (t < 15) STAGE(t + 1);  // prefetch next tile; latency hides under compute
    const u16* Kc = Ks[t & 1];
    const u16* Vc = Vs[t & 1];

    // swapped scores: s[mi][ni][r] = P^T, kv = ni*16+g*4+r, q = mi*16+lr
    f32x4 s[2][4];
#pragma unroll
    for (int ni = 0; ni < 4; ni++) {
      const int row = ni * 16 + lr;
      bf16x8 b0 = *(const bf16x8*)(Kc + row * 64 + ((g ^ (row & 7)) << 3));
      bf16x8 b1 = *(const bf16x8*)(Kc + row * 64 + (((4 + g) ^ (row & 7)) << 3));
#pragma unroll
      for (int mi = 0; mi < 2; mi++) {
        f32x4 z = MFMA(b0, aq[mi][0], zero);
        z = MFMA(b1, aq[mi][1], z);
        s[mi][ni] = z;
      }
    }
    // mask by kv (u8 vector load, kv-contiguous)
#pragma unroll
    for (int ni = 0; ni < 4; ni++) {
      const u8x4 mk4 = *(const u8x4*)(mlds8 + t * 64 + ni * 16 + g * 4);
#pragma unroll
      for (int mi = 0; mi < 2; mi++)
#pragma unroll
        for (int j = 0; j < 4; j++)
          s[mi][ni][j] = mk4[j] ? s[mi][ni][j] : -1e9f;
    }

    // P = exp2(s) -> packed bf16x4 -> per-wave LDS (same XOR swizzle as reads)
#pragma unroll
    for (int mi = 0; mi < 2; mi++) {
      const int prow = mi * 16 + lr;
      const int rbase = prow * 128, sw = (prow & 7) << 4;
#pragma unroll
      for (int ni = 0; ni < 4; ni++) {
        u16x4 pk;
#pragma unroll
        for (int j = 0; j < 4; j++)
          pk[j] = f2bf(__builtin_amdgcn_exp2f(s[mi][ni][j]));
        *(u16x4*)(Pw + ((rbase + ((ni * 32 + g * 8) ^ sw)) >> 1)) = pk;
      }
    }

    // PV + ones-MFMA row sums (ap reads byte-identical)
#pragma unroll
    for (int ks2 = 0; ks2 < 2; ks2++) {
      bf16x8 ap[2];
#pragma unroll
      for (int mi = 0; mi < 2; mi++) {
        const int prow = mi * 16 + lr;
        const int byt = prow * 128 + ((ks2 * 64 + g * 16) ^ ((prow & 7) << 4));
        ap[mi] = *(const bf16x8*)(Pw + (byt >> 1));
      }
#pragma unroll
      for (int di = 0; di < 4; di++) {
        const int vrow = di * 16 + lr;
        bf16x8 bv = *(const bf16x8*)(Vc + vrow * 64 + (((ks2 * 4 + g) ^ (vrow & 7)) << 3));
#pragma unroll
        for (int mi = 0; mi < 2; mi++)
          o[mi][di] = MFMA(ap[mi], bv, o[mi][di]);
      }
#pragma unroll
      for (int mi = 0; mi < 2; mi++)
        o_l[mi] = MFMA(ap[mi], ones, o_l[mi]);
    }

    if (t < 15) __syncthreads();  // full drain: prefetch landed, reads retired
  }
#undef STAGE

  // partial epilogue: unnormalized o (bf16) + l (f32)
  u16* opw = o_part + (size_t)(half * 24 + bh) * (2048 * 64);
  float* lpw = l_part + (size_t)(half * 24 + bh) * 2048;
#pragma unroll
  for (int mi = 0; mi < 2; mi++) {
#pragma unroll
    for (int di = 0; di < 4; di++)
#pragma unroll
      for (int j = 0; j < 4; j++) {
        const int row = q0 + mi * 16 + g * 4 + j;
        opw[(size_t)row * 64 + di * 16 + lr] = f2bf(o[mi][di][j]);
      }
    if (lr == 0) {
#pragma unroll
      for (int j = 0; j < 4; j++)
        lpw[q0 + mi * 16 + g * 4 + j] = o_l[mi][j];
    }
  }
}

// ---------------- combine partials -> attn (bf16, [B*S][768]) ----------------

__global__ __launch_bounds__(256) void k_combine(
    const u16* __restrict__ o_part, const float* __restrict__ l_part,
    u16* __restrict__ attn) {
  const int idx = blockIdx.x * 256 + threadIdx.x;  // 49152*8 threads
  const int row = idx >> 3;                        // [0, 49152): bh*2048 + s
  const int c8 = (idx & 7) << 3;
  const size_t HALF_O = (size_t)24 * 2048 * 64;
  u16x8 a0 = *(const u16x8*)(o_part + (size_t)row * 64 + c8);
  u16x8 a1 = *(const u16x8*)(o_part + HALF_O + (size_t)row * 64 + c8);
  const float l = l_part[row] + l_part[24 * 2048 + row];
  const float rcp = 1.0f / l;
  u16x8 r;
#pragma unroll
  for (int j = 0; j < 8; j++)
    r[j] = f2bf((bf2f(a0[j]) + bf2f(a1[j])) * rcp);
  const int bh = row >> 11, s = row & 2047;
  const int b = bh / 12, h = bh - b * 12;
  *(u16x8*)(attn + (size_t)(b * 2048 + s) * 768 + h * 64 + c8) = r;
}

// ---------------- output projection GEMM (dbuf + XCD work grouping) ---------

__global__ __launch_bounds__(256) void k_gemm_out(
    const u16* __restrict__ attn, const u16* __restrict__ wob,
    const float* __restrict__ bo, float* __restrict__ out) {
  __shared__ __align__(16) u16 As[2][128 * 32];
  __shared__ __align__(16) u16 Bs[2][128 * 32];
  const int tid = threadIdx.x;
  const int bid = blockIdx.x;
  const int wid = (bid & 7) * 24 + (bid >> 3);  // bijective: 192 = 8*24
  const int row0 = (wid / 6) * 128, col0 = (wid % 6) * 128;
  const int w = tid >> 6, lane = tid & 63, lr = lane & 15, kg = lane >> 4;
  const int wr = (w >> 1) * 64, wc = (w & 1) * 64;

  const int c0 = tid, c1 = tid + 256;
  const int r0c = c0 >> 2, g0 = (c0 & 3) ^ ((r0c >> 1) & 3);
  const int r1c = c1 >> 2, g1 = (c1 & 3) ^ ((r1c >> 1) & 3);
  const u16* aS0 = attn + (size_t)(row0 + r0c) * 768 + g0 * 8;
  const u16* aS1 = attn + (size_t)(row0 + r1c) * 768 + g1 * 8;
  const u16* bS0 = wob + (size_t)(col0 + r0c) * 768 + g0 * 8;
  const u16* bS1 = wob + (size_t)(col0 + r1c) * 768 + g1 * 8;

  f32x4 acc[4][4];
  f32x4 zero = {0.f, 0.f, 0.f, 0.f};
#pragma unroll
  for (int i = 0; i < 4; i++)
#pragma unroll
    for (int j = 0; j < 4; j++) acc[i][j] = zero;

  int aoff[4], boff[4];
#pragma unroll
  for (int mi = 0; mi < 4; mi++) {
    int r = wr + mi * 16 + lr;
    aoff[mi] = r * 32 + (kg ^ ((r >> 1) & 3)) * 8;
  }
#pragma unroll
  for (int ni = 0; ni < 4; ni++) {
    int r = wc + ni * 16 + lr;
    boff[ni] = r * 32 + (kg ^ ((r >> 1) & 3)) * 8;
  }

#define STAGE(kt) { u16* ad = As[(kt)&1]; u16* bd = Bs[(kt)&1];   \
    gll16(aS0 + (kt) * 32, ad + c0 * 8);                          \
    gll16(aS1 + (kt) * 32, ad + c1 * 8);                          \
    gll16(bS0 + (kt) * 32, bd + c0 * 8);                          \
    gll16(bS1 + (kt) * 32, bd + c1 * 8); }

  STAGE(0);
  __syncthreads();

  for (int kt = 0; kt < 24; kt++) {
    const int cur = kt & 1;
    if (kt < 23) STAGE(kt + 1);
    bf16x8 af[4], bfr[4];
#pragma unroll
    for (int mi = 0; mi < 4; mi++) af[mi] = *(const bf16x8*)(As[cur] + aoff[mi]);
#pragma unroll
    for (int ni = 0; ni < 4; ni++) bfr[ni] = *(const bf16x8*)(Bs[cur] + boff[ni]);
#pragma unroll
    for (int mi = 0; mi < 4; mi++)
#pragma unroll
      for (int ni = 0; ni < 4; ni++)
        acc[mi][ni] = MFMA(af[mi], bfr[ni], acc[mi][ni]);
    if (kt < 23) __syncthreads();  // drains prefetch (hidden under compute)
  }
#undef STAGE

#pragma unroll
  for (int ni = 0; ni < 4; ni++) {
    const int n = col0 + wc + ni * 16 + lr;
    const float bval = bo[n];
#pragma unroll
    for (int mi = 0; mi < 4; mi++)
#pragma unroll
      for (int j = 0; j < 4; j++) {
        const int m = row0 + wr + mi * 16 + kg * 4 + j;
        out[(size_t)m * 768 + n] = acc[mi][ni][j] + bval;
      }
  }
}

// ---------------- launch ----------------

extern "C" void kernel_launch(void* const* d_in, const int* in_sizes, int n_in,
                              void* d_out, int out_size, void* d_ws, size_t ws_size,
                              hipStream_t stream) {
  const float* q = (const float*)d_in[0];
  const float* k = (const float*)d_in[1];
  const float* v = (const float*)d_in[2];
  const int* mask = (const int*)d_in[3];
  const float* Wq = (const float*)d_in[4];
  const float* bq = (const float*)d_in[5];
  const float* Wk = (const float*)d_in[6];
  const float* bk = (const float*)d_in[7];
  const float* Wv = (const float*)d_in[8];
  const float* bv = (const float*)d_in[9];
  const float* Wo = (const float*)d_in[10];
  const float* bo = (const float*)d_in[11];
  float* out = (float*)d_out;

  u16* scratch = (u16*)d_ws;                      // o_part/l_part region
  u16* wqkv = scratch + (size_t)3 * 4096 * 768;   // 2304 x 768
  u16* wob = wqkv + (size_t)2304 * 768;           // 768 x 768
  u16* Qb = wob + (size_t)768 * 768;              // 24 x 2048 x 64
  u16* Kb = Qb + (size_t)4096 * 768;              // 24 x 2048 x 64
  u16* Vtb = Kb + (size_t)4096 * 768;             // 24 x 64 x 2048 (transposed)
  u16* attn = Vtb + (size_t)4096 * 768;           // 4096 x 768

  // KV-split partials: o_part 2 x 24 x 2048 x 64 bf16, l_part 2 x 24 x 2048 f32
  u16* o_part = scratch;
  float* l_part = (float*)(scratch + (size_t)2 * 24 * 2048 * 64);

  k_convert_w<<<dim3(2304), dim3(256), 0, stream>>>(Wq, Wk, Wv, Wo, wqkv, wob);
  k_gemm_qkv<<<dim3(1152), dim3(256), 0, stream>>>(q, k, v, wqkv, bq, bk, bv, Qb, Kb, Vtb);
  k_attn<<<dim3(768), dim3(256), 0, stream>>>(Qb, Kb, Vtb, mask, o_part, l_part);
  k_combine<<<dim3(1536), dim3(256), 0, stream>>>(o_part, l_part, attn);
  k_gemm_out<<<dim3(192), dim3(256), 0, stream>>>(attn, wob, bo, out);
}

// Round 18
// 107.487 us; speedup vs baseline: 1.1142x; 1.1142x over previous
//
#include <hip/hip_runtime.h>

typedef unsigned short u16;
typedef __attribute__((ext_vector_type(8))) __bf16 bf16x8;
typedef __attribute__((ext_vector_type(8))) short s16x8;
typedef __attribute__((ext_vector_type(8))) unsigned short u16x8;
typedef __attribute__((ext_vector_type(4))) float f32x4;
typedef __attribute__((ext_vector_type(4))) unsigned short u16x4;
typedef __attribute__((ext_vector_type(4))) float fl4;
typedef __attribute__((ext_vector_type(4))) int i32x4;
typedef __attribute__((ext_vector_type(4))) unsigned char u8x4;

#define MFMA(a, b, c) __builtin_amdgcn_mfma_f32_16x16x32_bf16((a), (b), (c), 0, 0, 0)
// 0.125 * log2(e): folds 1/sqrt(dk) and the exp->exp2 conversion into Q
#define QSC 0.18033688011112042f

// native RNE float->bf16
__device__ __forceinline__ u16 f2bf(float f) {
  __bf16 h = (__bf16)f;
  return __builtin_bit_cast(unsigned short, h);
}

__device__ __forceinline__ float bf2f(u16 u) {
  union { unsigned u; float f; } v; v.u = ((unsigned)u) << 16;
  return v.f;
}

__device__ __forceinline__ void gll16(const u16* g, u16* l) {
  typedef __attribute__((address_space(1))) unsigned int gu32;
  typedef __attribute__((address_space(3))) unsigned int lu32;
  __builtin_amdgcn_global_load_lds((gu32*)g, (lu32*)l, 16, 0, 0);
}

// ---------------- weight convert ----------------

__global__ __launch_bounds__(256) void k_convert_w(
    const float* __restrict__ Wq, const float* __restrict__ Wk,
    const float* __restrict__ Wv, const float* __restrict__ Wo,
    u16* __restrict__ wqkv, u16* __restrict__ wob) {
  const int n = 3072 * 192;  // 3072 rows x 192 groups of 4
  for (int i = blockIdx.x * 256 + threadIdx.x; i < n; i += gridDim.x * 256) {
    int row = i / 192;
    int col = (i - row * 192) * 4;
    const float* src; u16* dst; float sc = 1.0f;
    if (row < 768)       { src = Wq + row * 768;          dst = wqkv + row * 768; sc = QSC; }
    else if (row < 1536) { src = Wk + (row - 768) * 768;  dst = wqkv + row * 768; }
    else if (row < 2304) { src = Wv + (row - 1536) * 768; dst = wqkv + row * 768; }
    else                 { src = Wo + (row - 2304) * 768; dst = wob + (row - 2304) * 768; }
    fl4 f = *(const fl4*)(src + col);
    u16x4 o;
    o[0] = f2bf(f[0] * sc); o[1] = f2bf(f[1] * sc);
    o[2] = f2bf(f[2] * sc); o[3] = f2bf(f[3] * sc);
    *(u16x4*)(dst + col) = o;
  }
}

// ---------------- fused QKV GEMM (round-7 verbatim: 128x128, 2D grid) -------
// A operand read directly from f32 inputs (q/k/v), converted in-register and
// ds_written to the same swizzled-LDS bytes gll16 staging would produce.
// B (weights) prefetched 1-ahead via gll16. 2 barriers/iter. No XCD remap.

__global__ __launch_bounds__(256) void k_gemm_qkv(
    const float* __restrict__ xq, const float* __restrict__ xk,
    const float* __restrict__ xv, const u16* __restrict__ wqkv,
    const float* __restrict__ bq, const float* __restrict__ bk_,
    const float* __restrict__ bv_,
    u16* __restrict__ Qb, u16* __restrict__ Kb, u16* __restrict__ Vtb) {
  __shared__ __align__(16) u16 Abuf[2][128 * 32];
  __shared__ __align__(16) u16 Bbuf[2][128 * 32];
  const int tid = threadIdx.x;
  const int row0 = blockIdx.x * 128, col0 = blockIdx.y * 128;
  const int seg = col0 / 768;
  const float* A32 = (seg == 0) ? xq : ((seg == 1) ? xk : xv);
  const int w = tid >> 6, lane = tid & 63, lr = lane & 15, kg = lane >> 4;
  const int wr = (w >> 1) * 64, wc = (w & 1) * 64;

  const int c0 = tid, c1 = tid + 256;
  const int r0c = c0 >> 2, g0 = (c0 & 3) ^ ((r0c >> 1) & 3);
  const int r1c = c1 >> 2, g1 = (c1 & 3) ^ ((r1c >> 1) & 3);
  const float* aS0 = A32 + (size_t)(row0 + r0c) * 768 + g0 * 8;
  const float* aS1 = A32 + (size_t)(row0 + r1c) * 768 + g1 * 8;
  const u16* bS0 = wqkv + (size_t)(col0 + r0c) * 768 + g0 * 8;
  const u16* bS1 = wqkv + (size_t)(col0 + r1c) * 768 + g1 * 8;

  f32x4 acc[4][4];
  f32x4 zero = {0.f, 0.f, 0.f, 0.f};
#pragma unroll
  for (int i = 0; i < 4; i++)
#pragma unroll
    for (int j = 0; j < 4; j++) acc[i][j] = zero;

  int aoff[4], boff[4];
#pragma unroll
  for (int mi = 0; mi < 4; mi++) {
    int r = wr + mi * 16 + lr;
    aoff[mi] = r * 32 + (kg ^ ((r >> 1) & 3)) * 8;
  }
#pragma unroll
  for (int ni = 0; ni < 4; ni++) {
    int r = wc + ni * 16 + lr;
    boff[ni] = r * 32 + (kg ^ ((r >> 1) & 3)) * 8;
  }

  fl4 ar[4];
#define LOADA(kt) { ar[0] = *(const fl4*)(aS0 + (kt) * 32);       \
                    ar[1] = *(const fl4*)(aS0 + (kt) * 32 + 4);   \
                    ar[2] = *(const fl4*)(aS1 + (kt) * 32);       \
                    ar[3] = *(const fl4*)(aS1 + (kt) * 32 + 4); }
#define WRITEA(buf) { u16x8 t0, t1;                               \
    t0[0]=f2bf(ar[0][0]); t0[1]=f2bf(ar[0][1]); t0[2]=f2bf(ar[0][2]); t0[3]=f2bf(ar[0][3]); \
    t0[4]=f2bf(ar[1][0]); t0[5]=f2bf(ar[1][1]); t0[6]=f2bf(ar[1][2]); t0[7]=f2bf(ar[1][3]); \
    t1[0]=f2bf(ar[2][0]); t1[1]=f2bf(ar[2][1]); t1[2]=f2bf(ar[2][2]); t1[3]=f2bf(ar[2][3]); \
    t1[4]=f2bf(ar[3][0]); t1[5]=f2bf(ar[3][1]); t1[6]=f2bf(ar[3][2]); t1[7]=f2bf(ar[3][3]); \
    *(u16x8*)((buf) + c0 * 8) = t0; *(u16x8*)((buf) + c1 * 8) = t1; }
#define STAGEB(kt, buf) { gll16(bS0 + (kt) * 32, (buf) + c0 * 8); \
                          gll16(bS1 + (kt) * 32, (buf) + c1 * 8); }

  LOADA(0);
  STAGEB(0, Bbuf[0]);
  WRITEA(Abuf[0]);
  __syncthreads();  // drains B(0) DMA; A(0) writes visible

  for (int kt = 0; kt < 24; kt++) {
    const int cur = kt & 1;
    if (kt < 23) { LOADA(kt + 1); STAGEB(kt + 1, Bbuf[cur ^ 1]); }
    bf16x8 af[4], bfr[4];
#pragma unroll
    for (int mi = 0; mi < 4; mi++) af[mi] = *(const bf16x8*)(Abuf[cur] + aoff[mi]);
#pragma unroll
    for (int ni = 0; ni < 4; ni++) bfr[ni] = *(const bf16x8*)(Bbuf[cur] + boff[ni]);
#pragma unroll
    for (int mi = 0; mi < 4; mi++)
#pragma unroll
      for (int ni = 0; ni < 4; ni++)
        acc[mi][ni] = MFMA(af[mi], bfr[ni], acc[mi][ni]);
    __syncthreads();  // drains B(kt+1) DMA + LOADA (covered by compute); reads retired
    if (kt < 23) {
      WRITEA(Abuf[cur ^ 1]);
      __syncthreads();  // A(kt+1) writes visible before compute(kt+1)
    }
  }
#undef LOADA
#undef WRITEA
#undef STAGEB

  const float* bias = (seg == 0) ? bq : ((seg == 1) ? bk_ : bv_);
  const float bsc = (seg == 0) ? QSC : 1.0f;
  const int ncol0 = col0 - seg * 768;
#pragma unroll
  for (int ni = 0; ni < 4; ni++) {
    const int n = ncol0 + wc + ni * 16 + lr;
    const float bval = bias[n] * bsc;
    const int hh = n >> 6, dk = n & 63;
#pragma unroll
    for (int mi = 0; mi < 4; mi++)
#pragma unroll
      for (int j = 0; j < 4; j++) {
        const int m = row0 + wr + mi * 16 + kg * 4 + j;
        const int bb = m >> 11, ss = m & 2047;
        const u16 val = f2bf(acc[mi][ni][j] + bval);
        if (seg == 0)
          Qb[((size_t)((bb * 12 + hh) * 2048 + ss)) * 64 + dk] = val;
        else if (seg == 1)
          Kb[((size_t)((bb * 12 + hh) * 2048 + ss)) * 64 + dk] = val;
        else
          Vtb[((size_t)((bb * 12 + hh) * 64 + dk)) * 2048 + ss] = val;
      }
  }
}

// ---------------- flash attention (round-15 passing version, unchanged) -----

__global__ __launch_bounds__(256) void k_attn(
    const u16* __restrict__ Qb, const u16* __restrict__ Kb,
    const u16* __restrict__ Vtb, const int* __restrict__ mask,
    u16* __restrict__ o_part, float* __restrict__ l_part) {
  __shared__ __align__(16) u16 Ks[2][64 * 64];
  __shared__ __align__(16) u16 Vs[2][64 * 64];
  __shared__ __align__(16) u16 Ps[4][32 * 64];
  __shared__ __align__(4) unsigned char mlds8[1024];
  const int bid = blockIdx.x;
  const int wid = (bid & 7) * 96 + (bid >> 3);  // bijective: 768 = 8*96
  const int qt = wid & 15;       // q-tile [0,16)
  const int gh = wid >> 4;       // (bh,half) group [0,48)
  const int bh = gh >> 1, half = gh & 1;
  const int b = bh / 12;
  const int kvb = half << 10;  // 0 or 1024
  const int tid = threadIdx.x, w = tid >> 6, lane = tid & 63;
  const int lr = lane & 15, g = lane >> 4;
  const int q0 = qt * 128 + w * 32;
  const u16* Qh = Qb + (size_t)bh * (2048 * 64);
  const u16* Kh = Kb + (size_t)bh * (2048 * 64);
  const u16* Vh = Vtb + (size_t)bh * (64 * 2048);
  const int* mb = mask + b * 2048;
  u16* Pw = Ps[w];

  // this block's mask half -> LDS as u8 (one i32x4 load -> u8x4 store)
  {
    i32x4 m4 = *(const i32x4*)(mb + kvb + tid * 4);
    u8x4 m8;
    m8[0] = (unsigned char)m4[0]; m8[1] = (unsigned char)m4[1];
    m8[2] = (unsigned char)m4[2]; m8[3] = (unsigned char)m4[3];
    *(u8x4*)(mlds8 + tid * 4) = m8;
  }

  bf16x8 aq[2][2];
#pragma unroll
  for (int mi = 0; mi < 2; mi++)
#pragma unroll
    for (int ks = 0; ks < 2; ks++)
      aq[mi][ks] = *(const bf16x8*)(Qh + (q0 + mi * 16 + lr) * 64 + ks * 32 + g * 8);

  f32x4 zero = {0.f, 0.f, 0.f, 0.f};
  f32x4 o[2][4];
#pragma unroll
  for (int mi = 0; mi < 2; mi++)
#pragma unroll
    for (int di = 0; di < 4; di++) o[mi][di] = zero;
  f32x4 o_l[2];
  o_l[0] = zero; o_l[1] = zero;

  // ones B-fragment for row-sum MFMA (bf16 1.0 = 0x3F80)
  s16x8 ov = {0x3F80, 0x3F80, 0x3F80, 0x3F80, 0x3F80, 0x3F80, 0x3F80, 0x3F80};
  bf16x8 ones = __builtin_bit_cast(bf16x8, ov);

  // staging coords: 512 chunks/tile; row c>>3, pos c&7 <-> global chunk (c&7)^(row&7)
  const int c0 = tid, c1 = tid + 256;
  const int sr0 = c0 >> 3, sg0 = (c0 & 7) ^ (sr0 & 7);
  const int sr1 = c1 >> 3, sg1 = (c1 & 7) ^ (sr1 & 7);
  const u16* kA0 = Kh + (size_t)kvb * 64 + sr0 * 64 + sg0 * 8;
  const u16* kA1 = Kh + (size_t)kvb * 64 + sr1 * 64 + sg1 * 8;
  const u16* vA0 = Vh + sr0 * 2048 + kvb + sg0 * 8;
  const u16* vA1 = Vh + sr1 * 2048 + kvb + sg1 * 8;

#define STAGE(u) { u16* kd = Ks[(u)&1]; u16* vd = Vs[(u)&1];           \
    gll16(kA0 + (u) * 4096, kd + c0 * 8);                              \
    gll16(kA1 + (u) * 4096, kd + c1 * 8);                              \
    gll16(vA0 + (u) * 64,  vd + c0 * 8);                               \
    gll16(vA1 + (u) * 64,  vd + c1 * 8); }

  STAGE(0);
  __syncthreads();  // drains STAGE(0) DMA + mlds8 writes; all waves synced

  for (int t = 0; t < 16; t++) {
    if (t < 15) STAGE(t + 1);  // prefetch next tile; latency hides under compute
    const u16* Kc = Ks[t & 1];
    const u16* Vc = Vs[t & 1];

    // swapped scores: s[mi][ni][r] = P^T, kv = ni*16+g*4+r, q = mi*16+lr
    f32x4 s[2][4];
#pragma unroll
    for (int ni = 0; ni < 4; ni++) {
      const int row = ni * 16 + lr;
      bf16x8 b0 = *(const bf16x8*)(Kc + row * 64 + ((g ^ (row & 7)) << 3));
      bf16x8 b1 = *(const bf16x8*)(Kc + row * 64 + (((4 + g) ^ (row & 7)) << 3));
#pragma unroll
      for (int mi = 0; mi < 2; mi++) {
        f32x4 z = MFMA(b0, aq[mi][0], zero);
        z = MFMA(b1, aq[mi][1], z);
        s[mi][ni] = z;
      }
    }
    // mask by kv (u8 vector load, kv-contiguous)
#pragma unroll
    for (int ni = 0; ni < 4; ni++) {
      const u8x4 mk4 = *(const u8x4*)(mlds8 + t * 64 + ni * 16 + g * 4);
#pragma unroll
      for (int mi = 0; mi < 2; mi++)
#pragma unroll
        for (int j = 0; j < 4; j++)
          s[mi][ni][j] = mk4[j] ? s[mi][ni][j] : -1e9f;
    }

    // P = exp2(s) -> packed bf16x4 -> per-wave LDS (same XOR swizzle as reads)
#pragma unroll
    for (int mi = 0; mi < 2; mi++) {
      const int prow = mi * 16 + lr;
      const int rbase = prow * 128, sw = (prow & 7) << 4;
#pragma unroll
      for (int ni = 0; ni < 4; ni++) {
        u16x4 pk;
#pragma unroll
        for (int j = 0; j < 4; j++)
          pk[j] = f2bf(__builtin_amdgcn_exp2f(s[mi][ni][j]));
        *(u16x4*)(Pw + ((rbase + ((ni * 32 + g * 8) ^ sw)) >> 1)) = pk;
      }
    }

    // PV + ones-MFMA row sums (ap reads byte-identical)
#pragma unroll
    for (int ks2 = 0; ks2 < 2; ks2++) {
      bf16x8 ap[2];
#pragma unroll
      for (int mi = 0; mi < 2; mi++) {
        const int prow = mi * 16 + lr;
        const int byt = prow * 128 + ((ks2 * 64 + g * 16) ^ ((prow & 7) << 4));
        ap[mi] = *(const bf16x8*)(Pw + (byt >> 1));
      }
#pragma unroll
      for (int di = 0; di < 4; di++) {
        const int vrow = di * 16 + lr;
        bf16x8 bv = *(const bf16x8*)(Vc + vrow * 64 + (((ks2 * 4 + g) ^ (vrow & 7)) << 3));
#pragma unroll
        for (int mi = 0; mi < 2; mi++)
          o[mi][di] = MFMA(ap[mi], bv, o[mi][di]);
      }
#pragma unroll
      for (int mi = 0; mi < 2; mi++)
        o_l[mi] = MFMA(ap[mi], ones, o_l[mi]);
    }

    if (t < 15) __syncthreads();  // full drain: prefetch landed, reads retired
  }
#undef STAGE

  // partial epilogue: unnormalized o (bf16) + l (f32)
  u16* opw = o_part + (size_t)(half * 24 + bh) * (2048 * 64);
  float* lpw = l_part + (size_t)(half * 24 + bh) * 2048;
#pragma unroll
  for (int mi = 0; mi < 2; mi++) {
#pragma unroll
    for (int di = 0; di < 4; di++)
#pragma unroll
      for (int j = 0; j < 4; j++) {
        const int row = q0 + mi * 16 + g * 4 + j;
        opw[(size_t)row * 64 + di * 16 + lr] = f2bf(o[mi][di][j]);
      }
    if (lr == 0) {
#pragma unroll
      for (int j = 0; j < 4; j++)
        lpw[q0 + mi * 16 + g * 4 + j] = o_l[mi][j];
    }
  }
}

// ---------------- combine partials -> attn (bf16, [B*S][768]) ----------------

__global__ __launch_bounds__(256) void k_combine(
    const u16* __restrict__ o_part, const float* __restrict__ l_part,
    u16* __restrict__ attn) {
  const int idx = blockIdx.x * 256 + threadIdx.x;  // 49152*8 threads
  const int row = idx >> 3;                        // [0, 49152): bh*2048 + s
  const int c8 = (idx & 7) << 3;
  const size_t HALF_O = (size_t)24 * 2048 * 64;
  u16x8 a0 = *(const u16x8*)(o_part + (size_t)row * 64 + c8);
  u16x8 a1 = *(const u16x8*)(o_part + HALF_O + (size_t)row * 64 + c8);
  const float l = l_part[row] + l_part[24 * 2048 + row];
  const float rcp = 1.0f / l;
  u16x8 r;
#pragma unroll
  for (int j = 0; j < 8; j++)
    r[j] = f2bf((bf2f(a0[j]) + bf2f(a1[j])) * rcp);
  const int bh = row >> 11, s = row & 2047;
  const int b = bh / 12, h = bh - b * 12;
  *(u16x8*)(attn + (size_t)(b * 2048 + s) * 768 + h * 64 + c8) = r;
}

// ---------------- output projection GEMM (dbuf + XCD work grouping) ---------

__global__ __launch_bounds__(256) void k_gemm_out(
    const u16* __restrict__ attn, const u16* __restrict__ wob,
    const float* __restrict__ bo, float* __restrict__ out) {
  __shared__ __align__(16) u16 As[2][128 * 32];
  __shared__ __align__(16) u16 Bs[2][128 * 32];
  const int tid = threadIdx.x;
  const int bid = blockIdx.x;
  const int wid = (bid & 7) * 24 + (bid >> 3);  // bijective: 192 = 8*24
  const int row0 = (wid / 6) * 128, col0 = (wid % 6) * 128;
  const int w = tid >> 6, lane = tid & 63, lr = lane & 15, kg = lane >> 4;
  const int wr = (w >> 1) * 64, wc = (w & 1) * 64;

  const int c0 = tid, c1 = tid + 256;
  const int r0c = c0 >> 2, g0 = (c0 & 3) ^ ((r0c >> 1) & 3);
  const int r1c = c1 >> 2, g1 = (c1 & 3) ^ ((r1c >> 1) & 3);
  const u16* aS0 = attn + (size_t)(row0 + r0c) * 768 + g0 * 8;
  const u16* aS1 = attn + (size_t)(row0 + r1c) * 768 + g1 * 8;
  const u16* bS0 = wob + (size_t)(col0 + r0c) * 768 + g0 * 8;
  const u16* bS1 = wob + (size_t)(col0 + r1c) * 768 + g1 * 8;

  f32x4 acc[4][4];
  f32x4 zero = {0.f, 0.f, 0.f, 0.f};
#pragma unroll
  for (int i = 0; i < 4; i++)
#pragma unroll
    for (int j = 0; j < 4; j++) acc[i][j] = zero;

  int aoff[4], boff[4];
#pragma unroll
  for (int mi = 0; mi < 4; mi++) {
    int r = wr + mi * 16 + lr;
    aoff[mi] = r * 32 + (kg ^ ((r >> 1) & 3)) * 8;
  }
#pragma unroll
  for (int ni = 0; ni < 4; ni++) {
    int r = wc + ni * 16 + lr;
    boff[ni] = r * 32 + (kg ^ ((r >> 1) & 3)) * 8;
  }

#define STAGE(kt) { u16* ad = As[(kt)&1]; u16* bd = Bs[(kt)&1];   \
    gll16(aS0 + (kt) * 32, ad + c0 * 8);                          \
    gll16(aS1 + (kt) * 32, ad + c1 * 8);                          \
    gll16(bS0 + (kt) * 32, bd + c0 * 8);                          \
    gll16(bS1 + (kt) * 32, bd + c1 * 8); }

  STAGE(0);
  __syncthreads();

  for (int kt = 0; kt < 24; kt++) {
    const int cur = kt & 1;
    if (kt < 23) STAGE(kt + 1);
    bf16x8 af[4], bfr[4];
#pragma unroll
    for (int mi = 0; mi < 4; mi++) af[mi] = *(const bf16x8*)(As[cur] + aoff[mi]);
#pragma unroll
    for (int ni = 0; ni < 4; ni++) bfr[ni] = *(const bf16x8*)(Bs[cur] + boff[ni]);
#pragma unroll
    for (int mi = 0; mi < 4; mi++)
#pragma unroll
      for (int ni = 0; ni < 4; ni++)
        acc[mi][ni] = MFMA(af[mi], bfr[ni], acc[mi][ni]);
    if (kt < 23) __syncthreads();  // drains prefetch (hidden under compute)
  }
#undef STAGE

#pragma unroll
  for (int ni = 0; ni < 4; ni++) {
    const int n = col0 + wc + ni * 16 + lr;
    const float bval = bo[n];
#pragma unroll
    for (int mi = 0; mi < 4; mi++)
#pragma unroll
      for (int j = 0; j < 4; j++) {
        const int m = row0 + wr + mi * 16 + kg * 4 + j;
        out[(size_t)m * 768 + n] = acc[mi][ni][j] + bval;
      }
  }
}

// ---------------- launch ----------------

extern "C" void kernel_launch(void* const* d_in, const int* in_sizes, int n_in,
                              void* d_out, int out_size, void* d_ws, size_t ws_size,
                              hipStream_t stream) {
  const float* q = (const float*)d_in[0];
  const float* k = (const float*)d_in[1];
  const float* v = (const float*)d_in[2];
  const int* mask = (const int*)d_in[3];
  const float* Wq = (const float*)d_in[4];
  const float* bq = (const float*)d_in[5];
  const float* Wk = (const float*)d_in[6];
  const float* bk = (const float*)d_in[7];
  const float* Wv = (const float*)d_in[8];
  const float* bv = (const float*)d_in[9];
  const float* Wo = (const float*)d_in[10];
  const float* bo = (const float*)d_in[11];
  float* out = (float*)d_out;

  u16* scratch = (u16*)d_ws;                      // o_part/l_part region
  u16* wqkv = scratch + (size_t)3 * 4096 * 768;   // 2304 x 768
  u16* wob = wqkv + (size_t)2304 * 768;           // 768 x 768
  u16* Qb = wob + (size_t)768 * 768;              // 24 x 2048 x 64
  u16* Kb = Qb + (size_t)4096 * 768;              // 24 x 2048 x 64
  u16* Vtb = Kb + (size_t)4096 * 768;             // 24 x 64 x 2048 (transposed)
  u16* attn = Vtb + (size_t)4096 * 768;           // 4096 x 768

  // KV-split partials: o_part 2 x 24 x 2048 x 64 bf16, l_part 2 x 24 x 2048 f32
  u16* o_part = scratch;
  float* l_part = (float*)(scratch + (size_t)2 * 24 * 2048 * 64);

  k_convert_w<<<dim3(2304), dim3(256), 0, stream>>>(Wq, Wk, Wv, Wo, wqkv, wob);
  k_gemm_qkv<<<dim3(32, 18), dim3(256), 0, stream>>>(q, k, v, wqkv, bq, bk, bv, Qb, Kb, Vtb);
  k_attn<<<dim3(768), dim3(256), 0, stream>>>(Qb, Kb, Vtb, mask, o_part, l_part);
  k_combine<<<dim3(1536), dim3(256), 0, stream>>>(o_part, l_part, attn);
  k_gemm_out<<<dim3(192), dim3(256), 0, stream>>>(attn, wob, bo, out);
}

// Round 19
// 106.269 us; speedup vs baseline: 1.1269x; 1.0115x over previous
//
#include <hip/hip_runtime.h>

typedef unsigned short u16;
typedef __attribute__((ext_vector_type(8))) __bf16 bf16x8;
typedef __attribute__((ext_vector_type(8))) short s16x8;
typedef __attribute__((ext_vector_type(8))) unsigned short u16x8;
typedef __attribute__((ext_vector_type(4))) float f32x4;
typedef __attribute__((ext_vector_type(4))) unsigned short u16x4;
typedef __attribute__((ext_vector_type(4))) float fl4;
typedef __attribute__((ext_vector_type(4))) int i32x4;
typedef __attribute__((ext_vector_type(4))) unsigned char u8x4;

#define MFMA(a, b, c) __builtin_amdgcn_mfma_f32_16x16x32_bf16((a), (b), (c), 0, 0, 0)
// 0.125 * log2(e): folds 1/sqrt(dk) and the exp->exp2 conversion into Q
#define QSC 0.18033688011112042f

// native RNE float->bf16
__device__ __forceinline__ u16 f2bf(float f) {
  __bf16 h = (__bf16)f;
  return __builtin_bit_cast(unsigned short, h);
}

__device__ __forceinline__ float bf2f(u16 u) {
  union { unsigned u; float f; } v; v.u = ((unsigned)u) << 16;
  return v.f;
}

__device__ __forceinline__ void gll16(const u16* g, u16* l) {
  typedef __attribute__((address_space(1))) unsigned int gu32;
  typedef __attribute__((address_space(3))) unsigned int lu32;
  __builtin_amdgcn_global_load_lds((gu32*)g, (lu32*)l, 16, 0, 0);
}

// ---------------- weight convert ----------------

__global__ __launch_bounds__(256) void k_convert_w(
    const float* __restrict__ Wq, const float* __restrict__ Wk,
    const float* __restrict__ Wv, const float* __restrict__ Wo,
    u16* __restrict__ wqkv, u16* __restrict__ wob) {
  const int n = 3072 * 192;  // 3072 rows x 192 groups of 4
  for (int i = blockIdx.x * 256 + threadIdx.x; i < n; i += gridDim.x * 256) {
    int row = i / 192;
    int col = (i - row * 192) * 4;
    const float* src; u16* dst; float sc = 1.0f;
    if (row < 768)       { src = Wq + row * 768;          dst = wqkv + row * 768; sc = QSC; }
    else if (row < 1536) { src = Wk + (row - 768) * 768;  dst = wqkv + row * 768; }
    else if (row < 2304) { src = Wv + (row - 1536) * 768; dst = wqkv + row * 768; }
    else                 { src = Wo + (row - 2304) * 768; dst = wob + (row - 2304) * 768; }
    fl4 f = *(const fl4*)(src + col);
    u16x4 o;
    o[0] = f2bf(f[0] * sc); o[1] = f2bf(f[1] * sc);
    o[2] = f2bf(f[2] * sc); o[3] = f2bf(f[3] * sc);
    *(u16x4*)(dst + col) = o;
  }
}

// ---------------- fused QKV GEMM: 128x128, 2D grid, SINGLE barrier/iter -----
// Round-18 kernel with WRITEA moved before the barrier (second barrier gone).
// Hazards: WRITEA targets Abuf[cur^1]; compute(kt) reads Abuf[cur] (disjoint);
// other waves' reads of Abuf[cur^1] retired before the PREVIOUS barrier; next
// iteration's reads are after THIS barrier. ar's vmcnt wait is covered by the
// 16 MFMAs and drained by the barrier regardless.

__global__ __launch_bounds__(256) void k_gemm_qkv(
    const float* __restrict__ xq, const float* __restrict__ xk,
    const float* __restrict__ xv, const u16* __restrict__ wqkv,
    const float* __restrict__ bq, const float* __restrict__ bk_,
    const float* __restrict__ bv_,
    u16* __restrict__ Qb, u16* __restrict__ Kb, u16* __restrict__ Vtb) {
  __shared__ __align__(16) u16 Abuf[2][128 * 32];
  __shared__ __align__(16) u16 Bbuf[2][128 * 32];
  const int tid = threadIdx.x;
  const int row0 = blockIdx.x * 128, col0 = blockIdx.y * 128;
  const int seg = col0 / 768;
  const float* A32 = (seg == 0) ? xq : ((seg == 1) ? xk : xv);
  const int w = tid >> 6, lane = tid & 63, lr = lane & 15, kg = lane >> 4;
  const int wr = (w >> 1) * 64, wc = (w & 1) * 64;

  const int c0 = tid, c1 = tid + 256;
  const int r0c = c0 >> 2, g0 = (c0 & 3) ^ ((r0c >> 1) & 3);
  const int r1c = c1 >> 2, g1 = (c1 & 3) ^ ((r1c >> 1) & 3);
  const float* aS0 = A32 + (size_t)(row0 + r0c) * 768 + g0 * 8;
  const float* aS1 = A32 + (size_t)(row0 + r1c) * 768 + g1 * 8;
  const u16* bS0 = wqkv + (size_t)(col0 + r0c) * 768 + g0 * 8;
  const u16* bS1 = wqkv + (size_t)(col0 + r1c) * 768 + g1 * 8;

  f32x4 acc[4][4];
  f32x4 zero = {0.f, 0.f, 0.f, 0.f};
#pragma unroll
  for (int i = 0; i < 4; i++)
#pragma unroll
    for (int j = 0; j < 4; j++) acc[i][j] = zero;

  int aoff[4], boff[4];
#pragma unroll
  for (int mi = 0; mi < 4; mi++) {
    int r = wr + mi * 16 + lr;
    aoff[mi] = r * 32 + (kg ^ ((r >> 1) & 3)) * 8;
  }
#pragma unroll
  for (int ni = 0; ni < 4; ni++) {
    int r = wc + ni * 16 + lr;
    boff[ni] = r * 32 + (kg ^ ((r >> 1) & 3)) * 8;
  }

  fl4 ar[4];
#define LOADA(kt) { ar[0] = *(const fl4*)(aS0 + (kt) * 32);       \
                    ar[1] = *(const fl4*)(aS0 + (kt) * 32 + 4);   \
                    ar[2] = *(const fl4*)(aS1 + (kt) * 32);       \
                    ar[3] = *(const fl4*)(aS1 + (kt) * 32 + 4); }
#define WRITEA(buf) { u16x8 t0, t1;                               \
    t0[0]=f2bf(ar[0][0]); t0[1]=f2bf(ar[0][1]); t0[2]=f2bf(ar[0][2]); t0[3]=f2bf(ar[0][3]); \
    t0[4]=f2bf(ar[1][0]); t0[5]=f2bf(ar[1][1]); t0[6]=f2bf(ar[1][2]); t0[7]=f2bf(ar[1][3]); \
    t1[0]=f2bf(ar[2][0]); t1[1]=f2bf(ar[2][1]); t1[2]=f2bf(ar[2][2]); t1[3]=f2bf(ar[2][3]); \
    t1[4]=f2bf(ar[3][0]); t1[5]=f2bf(ar[3][1]); t1[6]=f2bf(ar[3][2]); t1[7]=f2bf(ar[3][3]); \
    *(u16x8*)((buf) + c0 * 8) = t0; *(u16x8*)((buf) + c1 * 8) = t1; }
#define STAGEB(kt, buf) { gll16(bS0 + (kt) * 32, (buf) + c0 * 8); \
                          gll16(bS1 + (kt) * 32, (buf) + c1 * 8); }

  LOADA(0);
  STAGEB(0, Bbuf[0]);
  WRITEA(Abuf[0]);
  __syncthreads();  // drains B(0) DMA; A(0) writes visible

  for (int kt = 0; kt < 24; kt++) {
    const int cur = kt & 1;
    if (kt < 23) { LOADA(kt + 1); STAGEB(kt + 1, Bbuf[cur ^ 1]); }
    bf16x8 af[4], bfr[4];
#pragma unroll
    for (int mi = 0; mi < 4; mi++) af[mi] = *(const bf16x8*)(Abuf[cur] + aoff[mi]);
#pragma unroll
    for (int ni = 0; ni < 4; ni++) bfr[ni] = *(const bf16x8*)(Bbuf[cur] + boff[ni]);
#pragma unroll
    for (int mi = 0; mi < 4; mi++)
#pragma unroll
      for (int ni = 0; ni < 4; ni++)
        acc[mi][ni] = MFMA(af[mi], bfr[ni], acc[mi][ni]);
    if (kt < 23) WRITEA(Abuf[cur ^ 1]);  // write next A-tile; disjoint from cur reads
    __syncthreads();  // single barrier: drains B-DMA + A loads; A writes visible
  }
#undef LOADA
#undef WRITEA
#undef STAGEB

  const float* bias = (seg == 0) ? bq : ((seg == 1) ? bk_ : bv_);
  const float bsc = (seg == 0) ? QSC : 1.0f;
  const int ncol0 = col0 - seg * 768;
#pragma unroll
  for (int ni = 0; ni < 4; ni++) {
    const int n = ncol0 + wc + ni * 16 + lr;
    const float bval = bias[n] * bsc;
    const int hh = n >> 6, dk = n & 63;
#pragma unroll
    for (int mi = 0; mi < 4; mi++)
#pragma unroll
      for (int j = 0; j < 4; j++) {
        const int m = row0 + wr + mi * 16 + kg * 4 + j;
        const int bb = m >> 11, ss = m & 2047;
        const u16 val = f2bf(acc[mi][ni][j] + bval);
        if (seg == 0)
          Qb[((size_t)((bb * 12 + hh) * 2048 + ss)) * 64 + dk] = val;
        else if (seg == 1)
          Kb[((size_t)((bb * 12 + hh) * 2048 + ss)) * 64 + dk] = val;
        else
          Vtb[((size_t)((bb * 12 + hh) * 64 + dk)) * 2048 + ss] = val;
      }
  }
}

// ---------------- flash attention (round-15/18 passing version, unchanged) --

__global__ __launch_bounds__(256) void k_attn(
    const u16* __restrict__ Qb, const u16* __restrict__ Kb,
    const u16* __restrict__ Vtb, const int* __restrict__ mask,
    u16* __restrict__ o_part, float* __restrict__ l_part) {
  __shared__ __align__(16) u16 Ks[2][64 * 64];
  __shared__ __align__(16) u16 Vs[2][64 * 64];
  __shared__ __align__(16) u16 Ps[4][32 * 64];
  __shared__ __align__(4) unsigned char mlds8[1024];
  const int bid = blockIdx.x;
  const int wid = (bid & 7) * 96 + (bid >> 3);  // bijective: 768 = 8*96
  const int qt = wid & 15;       // q-tile [0,16)
  const int gh = wid >> 4;       // (bh,half) group [0,48)
  const int bh = gh >> 1, half = gh & 1;
  const int b = bh / 12;
  const int kvb = half << 10;  // 0 or 1024
  const int tid = threadIdx.x, w = tid >> 6, lane = tid & 63;
  const int lr = lane & 15, g = lane >> 4;
  const int q0 = qt * 128 + w * 32;
  const u16* Qh = Qb + (size_t)bh * (2048 * 64);
  const u16* Kh = Kb + (size_t)bh * (2048 * 64);
  const u16* Vh = Vtb + (size_t)bh * (64 * 2048);
  const int* mb = mask + b * 2048;
  u16* Pw = Ps[w];

  // this block's mask half -> LDS as u8 (one i32x4 load -> u8x4 store)
  {
    i32x4 m4 = *(const i32x4*)(mb + kvb + tid * 4);
    u8x4 m8;
    m8[0] = (unsigned char)m4[0]; m8[1] = (unsigned char)m4[1];
    m8[2] = (unsigned char)m4[2]; m8[3] = (unsigned char)m4[3];
    *(u8x4*)(mlds8 + tid * 4) = m8;
  }

  bf16x8 aq[2][2];
#pragma unroll
  for (int mi = 0; mi < 2; mi++)
#pragma unroll
    for (int ks = 0; ks < 2; ks++)
      aq[mi][ks] = *(const bf16x8*)(Qh + (q0 + mi * 16 + lr) * 64 + ks * 32 + g * 8);

  f32x4 zero = {0.f, 0.f, 0.f, 0.f};
  f32x4 o[2][4];
#pragma unroll
  for (int mi = 0; mi < 2; mi++)
#pragma unroll
    for (int di = 0; di < 4; di++) o[mi][di] = zero;
  f32x4 o_l[2];
  o_l[0] = zero; o_l[1] = zero;

  // ones B-fragment for row-sum MFMA (bf16 1.0 = 0x3F80)
  s16x8 ov = {0x3F80, 0x3F80, 0x3F80, 0x3F80, 0x3F80, 0x3F80, 0x3F80, 0x3F80};
  bf16x8 ones = __builtin_bit_cast(bf16x8, ov);

  // staging coords: 512 chunks/tile; row c>>3, pos c&7 <-> global chunk (c&7)^(row&7)
  const int c0 = tid, c1 = tid + 256;
  const int sr0 = c0 >> 3, sg0 = (c0 & 7) ^ (sr0 & 7);
  const int sr1 = c1 >> 3, sg1 = (c1 & 7) ^ (sr1 & 7);
  const u16* kA0 = Kh + (size_t)kvb * 64 + sr0 * 64 + sg0 * 8;
  const u16* kA1 = Kh + (size_t)kvb * 64 + sr1 * 64 + sg1 * 8;
  const u16* vA0 = Vh + sr0 * 2048 + kvb + sg0 * 8;
  const u16* vA1 = Vh + sr1 * 2048 + kvb + sg1 * 8;

#define STAGE(u) { u16* kd = Ks[(u)&1]; u16* vd = Vs[(u)&1];           \
    gll16(kA0 + (u) * 4096, kd + c0 * 8);                              \
    gll16(kA1 + (u) * 4096, kd + c1 * 8);                              \
    gll16(vA0 + (u) * 64,  vd + c0 * 8);                               \
    gll16(vA1 + (u) * 64,  vd + c1 * 8); }

  STAGE(0);
  __syncthreads();  // drains STAGE(0) DMA + mlds8 writes; all waves synced

  for (int t = 0; t < 16; t++) {
    if (t < 15) STAGE(t + 1);  // prefetch next tile; latency hides under compute
    const u16* Kc = Ks[t & 1];
    const u16* Vc = Vs[t & 1];

    // swapped scores: s[mi][ni][r] = P^T, kv = ni*16+g*4+r, q = mi*16+lr
    f32x4 s[2][4];
#pragma unroll
    for (int ni = 0; ni < 4; ni++) {
      const int row = ni * 16 + lr;
      bf16x8 b0 = *(const bf16x8*)(Kc + row * 64 + ((g ^ (row & 7)) << 3));
      bf16x8 b1 = *(const bf16x8*)(Kc + row * 64 + (((4 + g) ^ (row & 7)) << 3));
#pragma unroll
      for (int mi = 0; mi < 2; mi++) {
        f32x4 z = MFMA(b0, aq[mi][0], zero);
        z = MFMA(b1, aq[mi][1], z);
        s[mi][ni] = z;
      }
    }
    // mask by kv (u8 vector load, kv-contiguous)
#pragma unroll
    for (int ni = 0; ni < 4; ni++) {
      const u8x4 mk4 = *(const u8x4*)(mlds8 + t * 64 + ni * 16 + g * 4);
#pragma unroll
      for (int mi = 0; mi < 2; mi++)
#pragma unroll
        for (int j = 0; j < 4; j++)
          s[mi][ni][j] = mk4[j] ? s[mi][ni][j] : -1e9f;
    }

    // P = exp2(s) -> packed bf16x4 -> per-wave LDS (same XOR swizzle as reads)
#pragma unroll
    for (int mi = 0; mi < 2; mi++) {
      const int prow = mi * 16 + lr;
      const int rbase = prow * 128, sw = (prow & 7) << 4;
#pragma unroll
      for (int ni = 0; ni < 4; ni++) {
        u16x4 pk;
#pragma unroll
        for (int j = 0; j < 4; j++)
          pk[j] = f2bf(__builtin_amdgcn_exp2f(s[mi][ni][j]));
        *(u16x4*)(Pw + ((rbase + ((ni * 32 + g * 8) ^ sw)) >> 1)) = pk;
      }
    }

    // PV + ones-MFMA row sums (ap reads byte-identical)
#pragma unroll
    for (int ks2 = 0; ks2 < 2; ks2++) {
      bf16x8 ap[2];
#pragma unroll
      for (int mi = 0; mi < 2; mi++) {
        const int prow = mi * 16 + lr;
        const int byt = prow * 128 + ((ks2 * 64 + g * 16) ^ ((prow & 7) << 4));
        ap[mi] = *(const bf16x8*)(Pw + (byt >> 1));
      }
#pragma unroll
      for (int di = 0; di < 4; di++) {
        const int vrow = di * 16 + lr;
        bf16x8 bv = *(const bf16x8*)(Vc + vrow * 64 + (((ks2 * 4 + g) ^ (vrow & 7)) << 3));
#pragma unroll
        for (int mi = 0; mi < 2; mi++)
          o[mi][di] = MFMA(ap[mi], bv, o[mi][di]);
      }
#pragma unroll
      for (int mi = 0; mi < 2; mi++)
        o_l[mi] = MFMA(ap[mi], ones, o_l[mi]);
    }

    if (t < 15) __syncthreads();  // full drain: prefetch landed, reads retired
  }
#undef STAGE

  // partial epilogue: unnormalized o (bf16) + l (f32)
  u16* opw = o_part + (size_t)(half * 24 + bh) * (2048 * 64);
  float* lpw = l_part + (size_t)(half * 24 + bh) * 2048;
#pragma unroll
  for (int mi = 0; mi < 2; mi++) {
#pragma unroll
    for (int di = 0; di < 4; di++)
#pragma unroll
      for (int j = 0; j < 4; j++) {
        const int row = q0 + mi * 16 + g * 4 + j;
        opw[(size_t)row * 64 + di * 16 + lr] = f2bf(o[mi][di][j]);
      }
    if (lr == 0) {
#pragma unroll
      for (int j = 0; j < 4; j++)
        lpw[q0 + mi * 16 + g * 4 + j] = o_l[mi][j];
    }
  }
}

// ---------------- combine partials -> attn (bf16, [B*S][768]) ----------------

__global__ __launch_bounds__(256) void k_combine(
    const u16* __restrict__ o_part, const float* __restrict__ l_part,
    u16* __restrict__ attn) {
  const int idx = blockIdx.x * 256 + threadIdx.x;  // 49152*8 threads
  const int row = idx >> 3;                        // [0, 49152): bh*2048 + s
  const int c8 = (idx & 7) << 3;
  const size_t HALF_O = (size_t)24 * 2048 * 64;
  u16x8 a0 = *(const u16x8*)(o_part + (size_t)row * 64 + c8);
  u16x8 a1 = *(const u16x8*)(o_part + HALF_O + (size_t)row * 64 + c8);
  const float l = l_part[row] + l_part[24 * 2048 + row];
  const float rcp = 1.0f / l;
  u16x8 r;
#pragma unroll
  for (int j = 0; j < 8; j++)
    r[j] = f2bf((bf2f(a0[j]) + bf2f(a1[j])) * rcp);
  const int bh = row >> 11, s = row & 2047;
  const int b = bh / 12, h = bh - b * 12;
  *(u16x8*)(attn + (size_t)(b * 2048 + s) * 768 + h * 64 + c8) = r;
}

// ---------------- output projection GEMM (dbuf + XCD work grouping) ---------

__global__ __launch_bounds__(256) void k_gemm_out(
    const u16* __restrict__ attn, const u16* __restrict__ wob,
    const float* __restrict__ bo, float* __restrict__ out) {
  __shared__ __align__(16) u16 As[2][128 * 32];
  __shared__ __align__(16) u16 Bs[2][128 * 32];
  const int tid = threadIdx.x;
  const int bid = blockIdx.x;
  const int wid = (bid & 7) * 24 + (bid >> 3);  // bijective: 192 = 8*24
  const int row0 = (wid / 6) * 128, col0 = (wid % 6) * 128;
  const int w = tid >> 6, lane = tid & 63, lr = lane & 15, kg = lane >> 4;
  const int wr = (w >> 1) * 64, wc = (w & 1) * 64;

  const int c0 = tid, c1 = tid + 256;
  const int r0c = c0 >> 2, g0 = (c0 & 3) ^ ((r0c >> 1) & 3);
  const int r1c = c1 >> 2, g1 = (c1 & 3) ^ ((r1c >> 1) & 3);
  const u16* aS0 = attn + (size_t)(row0 + r0c) * 768 + g0 * 8;
  const u16* aS1 = attn + (size_t)(row0 + r1c) * 768 + g1 * 8;
  const u16* bS0 = wob + (size_t)(col0 + r0c) * 768 + g0 * 8;
  const u16* bS1 = wob + (size_t)(col0 + r1c) * 768 + g1 * 8;

  f32x4 acc[4][4];
  f32x4 zero = {0.f, 0.f, 0.f, 0.f};
#pragma unroll
  for (int i = 0; i < 4; i++)
#pragma unroll
    for (int j = 0; j < 4; j++) acc[i][j] = zero;

  int aoff[4], boff[4];
#pragma unroll
  for (int mi = 0; mi < 4; mi++) {
    int r = wr + mi * 16 + lr;
    aoff[mi] = r * 32 + (kg ^ ((r >> 1) & 3)) * 8;
  }
#pragma unroll
  for (int ni = 0; ni < 4; ni++) {
    int r = wc + ni * 16 + lr;
    boff[ni] = r * 32 + (kg ^ ((r >> 1) & 3)) * 8;
  }

#define STAGE(kt) { u16* ad = As[(kt)&1]; u16* bd = Bs[(kt)&1];   \
    gll16(aS0 + (kt) * 32, ad + c0 * 8);                          \
    gll16(aS1 + (kt) * 32, ad + c1 * 8);                          \
    gll16(bS0 + (kt) * 32, bd + c0 * 8);                          \
    gll16(bS1 + (kt) * 32, bd + c1 * 8); }

  STAGE(0);
  __syncthreads();

  for (int kt = 0; kt < 24; kt++) {
    const int cur = kt & 1;
    if (kt < 23) STAGE(kt + 1);
    bf16x8 af[4], bfr[4];
#pragma unroll
    for (int mi = 0; mi < 4; mi++) af[mi] = *(const bf16x8*)(As[cur] + aoff[mi]);
#pragma unroll
    for (int ni = 0; ni < 4; ni++) bfr[ni] = *(const bf16x8*)(Bs[cur] + boff[ni]);
#pragma unroll
    for (int mi = 0; mi < 4; mi++)
#pragma unroll
      for (int ni = 0; ni < 4; ni++)
        acc[mi][ni] = MFMA(af[mi], bfr[ni], acc[mi][ni]);
    if (kt < 23) __syncthreads();  // drains prefetch (hidden under compute)
  }
#undef STAGE

#pragma unroll
  for (int ni = 0; ni < 4; ni++) {
    const int n = col0 + wc + ni * 16 + lr;
    const float bval = bo[n];
#pragma unroll
    for (int mi = 0; mi < 4; mi++)
#pragma unroll
      for (int j = 0; j < 4; j++) {
        const int m = row0 + wr + mi * 16 + kg * 4 + j;
        out[(size_t)m * 768 + n] = acc[mi][ni][j] + bval;
      }
  }
}

// ---------------- launch ----------------

extern "C" void kernel_launch(void* const* d_in, const int* in_sizes, int n_in,
                              void* d_out, int out_size, void* d_ws, size_t ws_size,
                              hipStream_t stream) {
  const float* q = (const float*)d_in[0];
  const float* k = (const float*)d_in[1];
  const float* v = (const float*)d_in[2];
  const int* mask = (const int*)d_in[3];
  const float* Wq = (const float*)d_in[4];
  const float* bq = (const float*)d_in[5];
  const float* Wk = (const float*)d_in[6];
  const float* bk = (const float*)d_in[7];
  const float* Wv = (const float*)d_in[8];
  const float* bv = (const float*)d_in[9];
  const float* Wo = (const float*)d_in[10];
  const float* bo = (const float*)d_in[11];
  float* out = (float*)d_out;

  u16* scratch = (u16*)d_ws;                      // o_part/l_part region
  u16* wqkv = scratch + (size_t)3 * 4096 * 768;   // 2304 x 768
  u16* wob = wqkv + (size_t)2304 * 768;           // 768 x 768
  u16* Qb = wob + (size_t)768 * 768;              // 24 x 2048 x 64
  u16* Kb = Qb + (size_t)4096 * 768;              // 24 x 2048 x 64
  u16* Vtb = Kb + (size_t)4096 * 768;             // 24 x 64 x 2048 (transposed)
  u16* attn = Vtb + (size_t)4096 * 768;           // 4096 x 768

  // KV-split partials: o_part 2 x 24 x 2048 x 64 bf16, l_part 2 x 24 x 2048 f32
  u16* o_part = scratch;
  float* l_part = (float*)(scratch + (size_t)2 * 24 * 2048 * 64);

  k_convert_w<<<dim3(2304), dim3(256), 0, stream>>>(Wq, Wk, Wv, Wo, wqkv, wob);
  k_gemm_qkv<<<dim3(32, 18), dim3(256), 0, stream>>>(q, k, v, wqkv, bq, bk, bv, Qb, Kb, Vtb);
  k_attn<<<dim3(768), dim3(256), 0, stream>>>(Qb, Kb, Vtb, mask, o_part, l_part);
  k_combine<<<dim3(1536), dim3(256), 0, stream>>>(o_part, l_part, attn);
  k_gemm_out<<<dim3(192), dim3(256), 0, stream>>>(attn, wob, bo, out);
}